// Round 5
// baseline (153.394 us; speedup 1.0000x reference)
//
#include <hip/hip_runtime.h>
#include <cstdint>
#include <cstring>
#include <vector>
#include <algorithm>

// CLOPLayer: out[b,c,k] = x[b,c, idx[k]], idx = seed-42-deterministic
// neighbor-swap permutation of the 224x224 grid (JAX threefry replicated
// bit-exactly on host at dlopen).
//
// R4/R5: the R2/R3 invariance (47us at both 118MB and 38MB HBM fetch) showed
// the kernel is cacheline-TRANSACTION-bound (scattered 4B gathers -> ~20 lines
// per wave-inst), not byte-bound. Fix: stage a 72-row toroidal window in LDS
// with dense float4 loads, emit 56 rows with dense float4 NT stores, resolving
// the permutation via ds_read_b32 from host-precomputed u16 LDS offsets. All
// global traffic is now sequential 16B/lane.
// R5 fix: __builtin_nontemporal_store needs a clang ext-vector, not HIP float4.

#define PH 224
#define PW 224
#define PN (PH * PW)   // 50176
#define NBC (128 * 3)  // 384 (b,c) slices

#define R_OUT 56       // output rows per block
#define HALO 8         // staged halo rows each side
#define S_ROWS (R_OUT + 2 * HALO)   // 72 staged rows
#define NWIN (PH / R_OUT)           // 4 windows per slice
#define KWIN (R_OUT * PW)           // 12544 outputs per window

typedef float f4v __attribute__((ext_vector_type(4)));
typedef unsigned short u4v __attribute__((ext_vector_type(4)));

// ---------------------------------------------------------------------------
// Threefry-2x32, 20 rounds — bit-exact replica of jax/_src/prng.py lowering.
// ---------------------------------------------------------------------------
static inline uint32_t rotl32(uint32_t v, int d) {
  return (v << d) | (v >> (32 - d));
}

static void tf2x32(uint32_t k0, uint32_t k1, uint32_t x0, uint32_t x1,
                   uint32_t& o0, uint32_t& o1) {
  const uint32_t ks0 = k0, ks1 = k1, ks2 = k0 ^ k1 ^ 0x1BD11BDAu;
  uint32_t v0 = x0 + ks0;
  uint32_t v1 = x1 + ks1;
  static const int ra[4] = {13, 15, 26, 6};
  static const int rb[4] = {17, 29, 16, 24};
#define R4X(rr)                             \
  do {                                      \
    for (int _i = 0; _i < 4; ++_i) {        \
      v0 += v1;                             \
      v1 = rotl32(v1, (rr)[_i]);            \
      v1 ^= v0;                             \
    }                                       \
  } while (0)
  R4X(ra); v0 += ks1; v1 += ks2 + 1u;
  R4X(rb); v0 += ks2; v1 += ks0 + 2u;
  R4X(ra); v0 += ks0; v1 += ks1 + 3u;
  R4X(rb); v0 += ks1; v1 += ks2 + 4u;
  R4X(ra); v0 += ks2; v1 += ks0 + 5u;
#undef R4X
  o0 = v0;
  o1 = v1;
}

static void jax_split2(uint32_t k0, uint32_t k1,
                       uint32_t& a0, uint32_t& a1, uint32_t& b0, uint32_t& b1) {
  tf2x32(k0, k1, 0u, 0u, a0, a1);
  tf2x32(k0, k1, 0u, 1u, b0, b1);
}

static inline uint32_t jax_rb32(uint32_t k0, uint32_t k1, uint32_t i) {
  uint32_t y0, y1;
  tf2x32(k0, k1, 0u, i, y0, y1);
  return y0 ^ y1;  // partitionable random_bits: bits1 ^ bits2
}

// ---------------------------------------------------------------------------
// Host-side bit-exact replication of _index_permute(jax.random.key(42), ...)
// ---------------------------------------------------------------------------
static std::vector<int> compute_perm() {
  const int n = PN;
  const uint32_t K0 = 0u, K1 = 42u;  // jax.random.key(42)

  uint32_t k1a, k1b, k2a, k2b;
  jax_split2(K0, K1, k1a, k1b, k2a, k2b);

  // order = permutation(k1, n): 2 rounds of stable sort by random_bits.
  std::vector<int> order(n);
  for (int i = 0; i < n; ++i) order[i] = i;
  uint32_t ck0 = k1a, ck1 = k1b;
  std::vector<std::pair<uint32_t, int>> kv(n);
  for (int round = 0; round < 2; ++round) {
    uint32_t nk0, nk1, sk0, sk1;
    jax_split2(ck0, ck1, nk0, nk1, sk0, sk1);
    ck0 = nk0; ck1 = nk1;
    for (int i = 0; i < n; ++i) {
      kv[i] = {jax_rb32(sk0, sk1, (uint32_t)i), order[i]};
    }
    std::stable_sort(kv.begin(), kv.end(),
                     [](const std::pair<uint32_t, int>& a,
                        const std::pair<uint32_t, int>& b) {
                       return a.first < b.first;
                     });
    for (int i = 0; i < n; ++i) order[i] = kv[i].second;
  }

  // rs = choice(k2, 5, (n,), p): fp32 cumsum + uniform + searchsorted(left).
  float probs[5] = {(float)(1.0 - 0.3), (float)(0.3 / 4), (float)(0.3 / 4),
                    (float)(0.3 / 4), (float)(0.3 / 4)};
  float pc[5];
  pc[0] = probs[0];
  for (int i = 1; i < 5; ++i) pc[i] = pc[i - 1] + probs[i];

  std::vector<uint8_t> rs(n);
  for (int i = 0; i < n; ++i) {
    uint32_t bits = jax_rb32(k2a, k2b, (uint32_t)i);
    uint32_t fb = (bits >> 9) | 0x3f800000u;
    float u;
    std::memcpy(&u, &fb, 4);
    u -= 1.0f;
    if (u < 0.0f) u = 0.0f;
    float r = pc[4] * (1.0f - u);
    int ind = (int)(std::lower_bound(pc, pc + 5, r) - pc);
    rs[i] = (uint8_t)ind;
  }

  // Sequential swap scan.
  std::vector<int> idx(n);
  for (int i = 0; i < n; ++i) idx[i] = i;
  for (int t = 0; t < n; ++t) {
    const int id = order[t];
    const int r = rs[t];
    const int i = id / PW, j = id % PW;
    int ip = i, jp = j;
    if (r == 1)      ip = (i + 1) % PH;
    else if (r == 2) ip = (i - 1 + PH) % PH;
    else if (r == 3) jp = (j + 1) % PW;
    else if (r == 4) jp = (j - 1 + PW) % PW;
    const int id2 = (r == 0) ? id : (ip * PW + jp);
    const int a = idx[id];
    const int b = idx[id2];
    idx[id]  = b;
    idx[id2] = a;
  }
  return idx;
}

// Load-time init (legal: runs at dlopen, before graph capture).
struct PermHolder {
  std::vector<int> h_idx;
  std::vector<uint16_t> h_lofs;  // [NWIN][KWIN] u16 LDS offsets
  int* d_idx = nullptr;
  uint16_t* d_lofs = nullptr;
  bool lds_ok = false;  // all sources within halo AND uploads succeeded

  PermHolder() {
    h_idx = compute_perm();

    // Build per-window LDS offset tables; verify the halo bound exactly.
    h_lofs.assign((size_t)NWIN * KWIN, 0);
    bool ok = true;
    for (int w = 0; w < NWIN && ok; ++w) {
      const int g0 = w * R_OUT - HALO;  // first staged row (mod PH)
      for (int kk = 0; kk < KWIN; ++kk) {
        const int k = w * KWIN + kk;    // rows are contiguous per window
        const int s = h_idx[k];
        const int srow = s / PW, scol = s % PW;
        int i = ((srow - g0) % PH + PH) % PH;
        if (i >= S_ROWS) { ok = false; break; }
        h_lofs[(size_t)w * KWIN + kk] = (uint16_t)(i * PW + scol);
      }
    }

    int* p = nullptr;
    if (hipMalloc(&p, PN * sizeof(int)) == hipSuccess &&
        hipMemcpy(p, h_idx.data(), PN * sizeof(int),
                  hipMemcpyHostToDevice) == hipSuccess) {
      d_idx = p;
    }
    if (ok) {
      uint16_t* q = nullptr;
      if (hipMalloc(&q, (size_t)NWIN * KWIN * sizeof(uint16_t)) == hipSuccess &&
          hipMemcpy(q, h_lofs.data(), (size_t)NWIN * KWIN * sizeof(uint16_t),
                    hipMemcpyHostToDevice) == hipSuccess) {
        d_lofs = q;
        lds_ok = true;
      }
    }
  }
};
static PermHolder g_perm;

// ---------------------------------------------------------------------------
// Fast path: LDS-staged permute. blockIdx.x = window (4), blockIdx.y = bc (384).
// Stage S_ROWS=72 toroidal rows (64.5 KB LDS) with dense float4 loads; emit
// R_OUT=56 rows with dense float4 NT stores via 4 ds_read_b32 each.
// ---------------------------------------------------------------------------
__global__ __launch_bounds__(256) void clop_lds(
    const float* __restrict__ x, const uint16_t* __restrict__ lofs,
    float* __restrict__ out) {
  __shared__ float tile[S_ROWS * PW];  // 72*224*4 = 64512 B

  const int w = blockIdx.x;
  const size_t bc = blockIdx.y;
  const int g0 = w * R_OUT - HALO;
  const float* xs = x + bc * PN;

  // Stage: S_ROWS rows, PW/4 = 56 float4 per row -> 4032 float4 total.
  for (int t = threadIdx.x; t < S_ROWS * (PW / 4); t += 256) {
    const int i = t / (PW / 4);
    const int j = (t % (PW / 4)) * 4;
    int g = g0 + i;
    if (g < 0) g += PH;
    else if (g >= PH) g -= PH;
    const f4v v = *(const f4v*)(xs + g * PW + j);
    *(f4v*)(tile + i * PW + j) = v;
  }
  __syncthreads();

  // Emit: KWIN/4 = 3136 float4 outputs.
  const uint16_t* lw = lofs + (size_t)w * KWIN;
  float* ob = out + bc * PN + (size_t)w * KWIN;
  for (int t = threadIdx.x; t < KWIN / 4; t += 256) {
    const u4v o4 = *(const u4v*)(lw + t * 4);
    f4v v;
    v.x = tile[o4.x];
    v.y = tile[o4.y];
    v.z = tile[o4.z];
    v.w = tile[o4.w];
    __builtin_nontemporal_store(v, (f4v*)(ob + t * 4));
  }
}

// ---------------------------------------------------------------------------
// Fallback (proven-correct R3 kernel): scalar gather, thread-per-k, 8 bc each.
// ---------------------------------------------------------------------------
__global__ __launch_bounds__(256) void clop_gather(
    const float* __restrict__ x, const int* __restrict__ idx,
    float* __restrict__ out) {
  const int k = blockIdx.x * 256 + threadIdx.x;
  const int s = idx[k];
  const size_t bc0 = (size_t)blockIdx.y * 8;
#pragma unroll
  for (int t = 0; t < 8; ++t) {
    const size_t bc = bc0 + t;
    out[bc * PN + k] = x[bc * PN + s];
  }
}

extern "C" void kernel_launch(void* const* d_in, const int* in_sizes, int n_in,
                              void* d_out, int out_size, void* d_ws,
                              size_t ws_size, hipStream_t stream) {
  const float* x = (const float*)d_in[0];
  float* out = (float*)d_out;

  if (g_perm.lds_ok) {
    dim3 grid(NWIN, NBC);  // (4, 384) = 1536 blocks
    clop_lds<<<grid, 256, 0, stream>>>(x, g_perm.d_lofs, out);
    return;
  }

  const int* idx;
  if (g_perm.d_idx != nullptr) {
    idx = g_perm.d_idx;
  } else {
    (void)hipMemcpyAsync(d_ws, g_perm.h_idx.data(), PN * sizeof(int),
                         hipMemcpyHostToDevice, stream);
    idx = (const int*)d_ws;
  }
  dim3 grid(PN / 256, NBC / 8);
  clop_gather<<<grid, 256, 0, stream>>>(x, idx, out);
}

// Round 6
// 133.924 us; speedup vs baseline: 1.1454x; 1.1454x over previous
//
#include <hip/hip_runtime.h>
#include <cstdint>
#include <cstring>
#include <vector>
#include <algorithm>

// CLOPLayer: out[b,c,k] = x[b,c, idx[k]], idx = seed-42-deterministic
// neighbor-swap permutation of the 224x224 grid (JAX threefry replicated
// bit-exactly on host at dlopen).
//
// R6: R5 proved the LDS-staged dense-16B structure has ideal traffic (48MB
// fetch / 75MB write) but was latency-bound: 64.5KB LDS -> 2 blocks/CU,
// occupancy 17.8%, all pipes idle. Fix: 32-row windows (S_ROWS=48, 43KB LDS)
// -> 3 blocks/CU x 512 threads = 24 waves/CU, 2688 blocks; emit offsets
// prefetched into registers BEFORE the stage loop so their global-load latency
// hides behind staging.

#define PH 224
#define PW 224
#define PN (PH * PW)   // 50176
#define NBC (128 * 3)  // 384 (b,c) slices

#define R_OUT 32       // output rows per block
#define HALO 8         // staged halo rows each side
#define S_ROWS (R_OUT + 2 * HALO)   // 48 staged rows
#define NWIN (PH / R_OUT)           // 7 windows per slice
#define KWIN (R_OUT * PW)           // 7168 outputs per window
#define TPB 512
#define STAGE_F4 (S_ROWS * (PW / 4))  // 2688
#define EMIT_F4 (KWIN / 4)            // 1792

typedef float f4v __attribute__((ext_vector_type(4)));
typedef unsigned short u4v __attribute__((ext_vector_type(4)));

// ---------------------------------------------------------------------------
// Threefry-2x32, 20 rounds — bit-exact replica of jax/_src/prng.py lowering.
// ---------------------------------------------------------------------------
static inline uint32_t rotl32(uint32_t v, int d) {
  return (v << d) | (v >> (32 - d));
}

static void tf2x32(uint32_t k0, uint32_t k1, uint32_t x0, uint32_t x1,
                   uint32_t& o0, uint32_t& o1) {
  const uint32_t ks0 = k0, ks1 = k1, ks2 = k0 ^ k1 ^ 0x1BD11BDAu;
  uint32_t v0 = x0 + ks0;
  uint32_t v1 = x1 + ks1;
  static const int ra[4] = {13, 15, 26, 6};
  static const int rb[4] = {17, 29, 16, 24};
#define R4X(rr)                             \
  do {                                      \
    for (int _i = 0; _i < 4; ++_i) {        \
      v0 += v1;                             \
      v1 = rotl32(v1, (rr)[_i]);            \
      v1 ^= v0;                             \
    }                                       \
  } while (0)
  R4X(ra); v0 += ks1; v1 += ks2 + 1u;
  R4X(rb); v0 += ks2; v1 += ks0 + 2u;
  R4X(ra); v0 += ks0; v1 += ks1 + 3u;
  R4X(rb); v0 += ks1; v1 += ks2 + 4u;
  R4X(ra); v0 += ks2; v1 += ks0 + 5u;
#undef R4X
  o0 = v0;
  o1 = v1;
}

static void jax_split2(uint32_t k0, uint32_t k1,
                       uint32_t& a0, uint32_t& a1, uint32_t& b0, uint32_t& b1) {
  tf2x32(k0, k1, 0u, 0u, a0, a1);
  tf2x32(k0, k1, 0u, 1u, b0, b1);
}

static inline uint32_t jax_rb32(uint32_t k0, uint32_t k1, uint32_t i) {
  uint32_t y0, y1;
  tf2x32(k0, k1, 0u, i, y0, y1);
  return y0 ^ y1;  // partitionable random_bits: bits1 ^ bits2
}

// ---------------------------------------------------------------------------
// Host-side bit-exact replication of _index_permute(jax.random.key(42), ...)
// ---------------------------------------------------------------------------
static std::vector<int> compute_perm() {
  const int n = PN;
  const uint32_t K0 = 0u, K1 = 42u;  // jax.random.key(42)

  uint32_t k1a, k1b, k2a, k2b;
  jax_split2(K0, K1, k1a, k1b, k2a, k2b);

  // order = permutation(k1, n): 2 rounds of stable sort by random_bits.
  std::vector<int> order(n);
  for (int i = 0; i < n; ++i) order[i] = i;
  uint32_t ck0 = k1a, ck1 = k1b;
  std::vector<std::pair<uint32_t, int>> kv(n);
  for (int round = 0; round < 2; ++round) {
    uint32_t nk0, nk1, sk0, sk1;
    jax_split2(ck0, ck1, nk0, nk1, sk0, sk1);
    ck0 = nk0; ck1 = nk1;
    for (int i = 0; i < n; ++i) {
      kv[i] = {jax_rb32(sk0, sk1, (uint32_t)i), order[i]};
    }
    std::stable_sort(kv.begin(), kv.end(),
                     [](const std::pair<uint32_t, int>& a,
                        const std::pair<uint32_t, int>& b) {
                       return a.first < b.first;
                     });
    for (int i = 0; i < n; ++i) order[i] = kv[i].second;
  }

  // rs = choice(k2, 5, (n,), p): fp32 cumsum + uniform + searchsorted(left).
  float probs[5] = {(float)(1.0 - 0.3), (float)(0.3 / 4), (float)(0.3 / 4),
                    (float)(0.3 / 4), (float)(0.3 / 4)};
  float pc[5];
  pc[0] = probs[0];
  for (int i = 1; i < 5; ++i) pc[i] = pc[i - 1] + probs[i];

  std::vector<uint8_t> rs(n);
  for (int i = 0; i < n; ++i) {
    uint32_t bits = jax_rb32(k2a, k2b, (uint32_t)i);
    uint32_t fb = (bits >> 9) | 0x3f800000u;
    float u;
    std::memcpy(&u, &fb, 4);
    u -= 1.0f;
    if (u < 0.0f) u = 0.0f;
    float r = pc[4] * (1.0f - u);
    int ind = (int)(std::lower_bound(pc, pc + 5, r) - pc);
    rs[i] = (uint8_t)ind;
  }

  // Sequential swap scan.
  std::vector<int> idx(n);
  for (int i = 0; i < n; ++i) idx[i] = i;
  for (int t = 0; t < n; ++t) {
    const int id = order[t];
    const int r = rs[t];
    const int i = id / PW, j = id % PW;
    int ip = i, jp = j;
    if (r == 1)      ip = (i + 1) % PH;
    else if (r == 2) ip = (i - 1 + PH) % PH;
    else if (r == 3) jp = (j + 1) % PW;
    else if (r == 4) jp = (j - 1 + PW) % PW;
    const int id2 = (r == 0) ? id : (ip * PW + jp);
    const int a = idx[id];
    const int b = idx[id2];
    idx[id]  = b;
    idx[id2] = a;
  }
  return idx;
}

// Load-time init (legal: runs at dlopen, before graph capture).
struct PermHolder {
  std::vector<int> h_idx;
  std::vector<uint16_t> h_lofs;  // [NWIN][KWIN] u16 LDS offsets
  int* d_idx = nullptr;
  uint16_t* d_lofs = nullptr;
  bool lds_ok = false;  // all sources within halo AND uploads succeeded

  PermHolder() {
    h_idx = compute_perm();

    // Build per-window LDS offset tables; verify the halo bound exactly.
    h_lofs.assign((size_t)NWIN * KWIN, 0);
    bool ok = true;
    for (int w = 0; w < NWIN && ok; ++w) {
      const int g0 = w * R_OUT - HALO;  // first staged row (mod PH)
      for (int kk = 0; kk < KWIN; ++kk) {
        const int k = w * KWIN + kk;    // rows are contiguous per window
        const int s = h_idx[k];
        const int srow = s / PW, scol = s % PW;
        int i = ((srow - g0) % PH + PH) % PH;
        if (i >= S_ROWS) { ok = false; break; }
        h_lofs[(size_t)w * KWIN + kk] = (uint16_t)(i * PW + scol);
      }
    }

    int* p = nullptr;
    if (hipMalloc(&p, PN * sizeof(int)) == hipSuccess &&
        hipMemcpy(p, h_idx.data(), PN * sizeof(int),
                  hipMemcpyHostToDevice) == hipSuccess) {
      d_idx = p;
    }
    if (ok) {
      uint16_t* q = nullptr;
      if (hipMalloc(&q, (size_t)NWIN * KWIN * sizeof(uint16_t)) == hipSuccess &&
          hipMemcpy(q, h_lofs.data(), (size_t)NWIN * KWIN * sizeof(uint16_t),
                    hipMemcpyHostToDevice) == hipSuccess) {
        d_lofs = q;
        lds_ok = true;
      }
    }
  }
};
static PermHolder g_perm;

// ---------------------------------------------------------------------------
// Fast path: LDS-staged permute. blockIdx.x = window (7), blockIdx.y = bc (384).
// 512 threads, 43KB LDS -> 3 blocks/CU (24 waves). Offsets prefetched into
// registers before staging so their latency hides behind the stage loads.
// ---------------------------------------------------------------------------
__global__ __launch_bounds__(TPB) void clop_lds(
    const float* __restrict__ x, const uint16_t* __restrict__ lofs,
    float* __restrict__ out) {
  __shared__ float tile[S_ROWS * PW];  // 48*224*4 = 43008 B

  const int w = blockIdx.x;
  const size_t bc = blockIdx.y;
  const int g0 = w * R_OUT - HALO;
  const float* xs = x + bc * PN;

  // Prefetch emit offsets (independent of LDS; latency hides behind staging).
  const uint16_t* lw = lofs + (size_t)w * KWIN;
  u4v o4[4];
#pragma unroll
  for (int i = 0; i < 4; ++i) {
    const int t = (int)threadIdx.x + i * TPB;
    if (t < EMIT_F4) o4[i] = *(const u4v*)(lw + t * 4);
  }

  // Stage: S_ROWS toroidal rows, dense float4 loads. 2688 f4 / 512 thr.
#pragma unroll
  for (int i = 0; i < 6; ++i) {
    const int t = (int)threadIdx.x + i * TPB;
    if (t < STAGE_F4) {
      const int r = t / (PW / 4);
      const int j = (t % (PW / 4)) * 4;
      int g = g0 + r;
      if (g < 0) g += PH;
      else if (g >= PH) g -= PH;
      *(f4v*)(tile + r * PW + j) = *(const f4v*)(xs + g * PW + j);
    }
  }
  __syncthreads();

  // Emit: 1792 f4 outputs via 4x ds_read_b32 each, dense NT stores.
  float* ob = out + bc * PN + (size_t)w * KWIN;
#pragma unroll
  for (int i = 0; i < 4; ++i) {
    const int t = (int)threadIdx.x + i * TPB;
    if (t < EMIT_F4) {
      f4v v;
      v.x = tile[o4[i].x];
      v.y = tile[o4[i].y];
      v.z = tile[o4[i].z];
      v.w = tile[o4[i].w];
      __builtin_nontemporal_store(v, (f4v*)(ob + t * 4));
    }
  }
}

// ---------------------------------------------------------------------------
// Fallback (proven-correct R3 kernel): scalar gather, thread-per-k, 8 bc each.
// ---------------------------------------------------------------------------
__global__ __launch_bounds__(256) void clop_gather(
    const float* __restrict__ x, const int* __restrict__ idx,
    float* __restrict__ out) {
  const int k = blockIdx.x * 256 + threadIdx.x;
  const int s = idx[k];
  const size_t bc0 = (size_t)blockIdx.y * 8;
#pragma unroll
  for (int t = 0; t < 8; ++t) {
    const size_t bc = bc0 + t;
    out[bc * PN + k] = x[bc * PN + s];
  }
}

extern "C" void kernel_launch(void* const* d_in, const int* in_sizes, int n_in,
                              void* d_out, int out_size, void* d_ws,
                              size_t ws_size, hipStream_t stream) {
  const float* x = (const float*)d_in[0];
  float* out = (float*)d_out;

  if (g_perm.lds_ok) {
    dim3 grid(NWIN, NBC);  // (7, 384) = 2688 blocks
    clop_lds<<<grid, TPB, 0, stream>>>(x, g_perm.d_lofs, out);
    return;
  }

  const int* idx;
  if (g_perm.d_idx != nullptr) {
    idx = g_perm.d_idx;
  } else {
    (void)hipMemcpyAsync(d_ws, g_perm.h_idx.data(), PN * sizeof(int),
                         hipMemcpyHostToDevice, stream);
    idx = (const int*)d_ws;
  }
  dim3 grid(PN / 256, NBC / 8);
  clop_gather<<<grid, 256, 0, stream>>>(x, idx, out);
}